// Round 1
// baseline (228.503 us; speedup 1.0000x reference)
//
#include <hip/hip_runtime.h>
#include <hip/hip_bf16.h>
#include <cstdint>

#define B_ 16
#define S_ 2048
#define H_ 1024
#define D_ 64
#define R_ 2048
#define M_ (B_*S_)   // 32768 rows
#define N_ 128       // 2*D

typedef short short8 __attribute__((ext_vector_type(8)));
typedef float f32x4  __attribute__((ext_vector_type(4)));

__device__ __forceinline__ unsigned short f2bf(float f) {
    unsigned u = __builtin_bit_cast(unsigned, f);
    u += 0x7FFFu + ((u >> 16) & 1u);     // round-to-nearest-even
    return (unsigned short)(u >> 16);
}

// ---------------------------------------------------------------------------
// Kernel 0: Wt[n][k] = bf16(W[k][n]);  Wt is [128][1024] ushort in workspace.
// ---------------------------------------------------------------------------
__global__ void build_wt(const float* __restrict__ W, unsigned short* __restrict__ Wt) {
    int o = blockIdx.x * 256 + threadIdx.x;      // 131072 total
    int n = o >> 10, k = o & 1023;
    Wt[o] = f2bf(W[k * N_ + n]);
}

// ---------------------------------------------------------------------------
// Kernel 1: C[m][0:128] = A[m][:] @ W + b, then RoPE, written fp32 to qk ws.
// Block = 256 thr = 4 waves; wave owns 16 rows x 128 cols (8 MFMA tiles).
// A-fragments loaded straight from global (fp32 -> bf16 in regs), register
// double-buffered per 64-wide K chunk. W chunk staged in LDS, XOR-swizzled.
// ---------------------------------------------------------------------------
__launch_bounds__(256, 2)
__global__ void gemm_rope(const float* __restrict__ A,            // [M][1024]
                          const unsigned short* __restrict__ Wt,  // [128][1024] bf16
                          const float* __restrict__ bias,         // [128]
                          const int* __restrict__ pos_ids,        // [M] (flattened B,S)
                          float* __restrict__ qk)                 // [M][128] fp32
{
    __shared__ unsigned short lw[N_ * 64];       // 16 KiB, swizzled [n][64]

    const int tid  = threadIdx.x;
    const int wave = tid >> 6, lane = tid & 63;
    const int ln15 = lane & 15, quad = lane >> 4;
    const int m    = blockIdx.x * 64 + wave * 16 + ln15;     // A-frag row
    const float* arow = A + (size_t)m * H_ + quad * 8;       // k-offset quad*8

    f32x4 acc[8];
    #pragma unroll
    for (int j = 0; j < 8; j++) acc[j] = (f32x4)0.f;

    // W staging mapping: thread -> (n = tid/2, half = tid&1), 4 granules of 8 bf16
    const int wn = tid >> 1, wh = tid & 1;
    const unsigned short* wsrc = Wt + wn * H_ + wh * 32;
    unsigned short* wdst = lw + wn * 64;
    const int wn7 = wn & 7;

    f32x4 a_cur[4], a_nxt[4];
    #pragma unroll
    for (int i = 0; i < 4; i++)
        a_cur[i] = *(const f32x4*)(arow + ((i >> 1) * 32) + ((i & 1) * 4));

    for (int kc = 0; kc < H_; kc += 64) {
        // ---- stage W chunk (128 x 64 bf16) into LDS, swizzled
        #pragma unroll
        for (int g = 0; g < 4; g++) {
            int gg = wh * 4 + g;                               // granule: k = gg*8
            short8 v = *(const short8*)(wsrc + kc + g * 8);
            *(short8*)(wdst + ((gg ^ wn7) * 8)) = v;
        }
        __syncthreads();

        // ---- prefetch next A chunk while computing this one
        if (kc + 64 < H_) {
            #pragma unroll
            for (int i = 0; i < 4; i++)
                a_nxt[i] = *(const f32x4*)(arow + (kc + 64) + ((i >> 1) * 32) + ((i & 1) * 4));
        }

        #pragma unroll
        for (int ks = 0; ks < 2; ks++) {
            short8 af;
            #pragma unroll
            for (int i = 0; i < 4; i++) {
                af[i]     = (short)f2bf(a_cur[2 * ks][i]);
                af[i + 4] = (short)f2bf(a_cur[2 * ks + 1][i]);
            }
            const int swz = ((ks * 4 + quad) ^ (ln15 & 7)) * 8;
            #pragma unroll
            for (int j = 0; j < 8; j++) {
                short8 bf = *(const short8*)(lw + (j * 16 + ln15) * 64 + swz);
                acc[j] = __builtin_amdgcn_mfma_f32_16x16x32_bf16(af, bf, acc[j], 0, 0, 0);
            }
        }
        __syncthreads();
        #pragma unroll
        for (int i = 0; i < 4; i++) a_cur[i] = a_nxt[i];
    }

    // ---- epilogue: bias + RoPE, write fp32
    // C/D layout: col = lane&15 (within 16-col tile j), row = quad*4 + reg
    const int rbase = blockIdx.x * 64 + wave * 16 + quad * 4;
    #pragma unroll
    for (int reg = 0; reg < 4; reg++) {
        const int r = rbase + reg;
        const float pos = (float)pos_ids[r];
        #pragma unroll
        for (int j = 0; j < 8; j++) {
            const int c = j * 16 + ln15;
            float v = acc[j][reg] + bias[c];
            float p = __shfl_xor(v, 1, 64);          // partner column c^1 (incl. its bias)
            const int fi = (c & 63) >> 1;            // freq index within q/k half
            // inv_freq = 10000^(-fi/32) = exp2(-fi * log2(10000)/32)
            const float ang = pos * exp2f((float)fi * -0.41524101186092029f);
            float s, co;
            sincosf(ang, &s, &co);
            const float outv = (ln15 & 1) ? (v * co + p * s) : (v * co - p * s);
            qk[(size_t)r * N_ + c] = outv;
        }
    }
}

// ---------------------------------------------------------------------------
// Kernel 2: one wave per relation. logits = qw[i0].kw[i2] + qw[i1].kw[i3]
// ---------------------------------------------------------------------------
__global__ void gather_dot(const float* __restrict__ qk, const int* __restrict__ rel,
                           const float* __restrict__ mask, float* __restrict__ out)
{
    const int w    = (blockIdx.x * 256 + threadIdx.x) >> 6;   // relation id 0..32767
    const int lane = threadIdx.x & 63;
    const int b = w >> 11;                                    // / R_
    const int4 id4 = ((const int4*)rel)[w];
    const float* base = qk + (size_t)b * S_ * N_;
    float v = base[(size_t)id4.x * N_ + lane]      * base[(size_t)id4.z * N_ + 64 + lane]
            + base[(size_t)id4.y * N_ + lane]      * base[(size_t)id4.w * N_ + 64 + lane];
    #pragma unroll
    for (int off = 32; off; off >>= 1) v += __shfl_xor(v, off, 64);
    if (lane == 0)
        out[w] = (v + (1.0f - mask[w]) * -1e12f) * 0.125f;
}

// ---------------------------------------------------------------------------
extern "C" void kernel_launch(void* const* d_in, const int* in_sizes, int n_in,
                              void* d_out, int out_size, void* d_ws, size_t ws_size,
                              hipStream_t stream) {
    const float* lhs  = (const float*)d_in[0];   // (B,S,H) fp32
    const float* W    = (const float*)d_in[1];   // (H,128) fp32
    const float* bias = (const float*)d_in[2];   // (128,)  fp32
    const int*   pos  = (const int*)d_in[3];     // (B,S)   int32
    const int*   rel  = (const int*)d_in[4];     // (B,R,4) int32
    const float* mask = (const float*)d_in[5];   // (B,R)   fp32
    float* out = (float*)d_out;                  // (B,R)   fp32

    unsigned short* Wt = (unsigned short*)d_ws;                     // 256 KiB
    float* qk = (float*)((char*)d_ws + (size_t)N_ * H_ * 2);        // 16 MiB

    build_wt<<<512, 256, 0, stream>>>(W, Wt);
    gemm_rope<<<512, 256, 0, stream>>>(lhs, Wt, bias, pos, qk);
    gather_dot<<<8192, 256, 0, stream>>>(qk, rel, mask, out);
}

// Round 2
// 220.578 us; speedup vs baseline: 1.0359x; 1.0359x over previous
//
#include <hip/hip_runtime.h>
#include <hip/hip_bf16.h>
#include <cstdint>

#define B_ 16
#define S_ 2048
#define H_ 1024
#define D_ 64
#define R_ 2048
#define M_ (B_*S_)   // 32768 rows
#define N_ 128       // 2*D
#define NC_ 16       // K chunks of 64

typedef short short8 __attribute__((ext_vector_type(8)));
typedef float f32x4  __attribute__((ext_vector_type(4)));

__device__ __forceinline__ unsigned short f2bf(float f) {
    unsigned u = __builtin_bit_cast(unsigned, f);
    u += 0x7FFFu + ((u >> 16) & 1u);     // RNE
    return (unsigned short)(u >> 16);
}
__device__ __forceinline__ unsigned pk2(float a, float b) {
    return (unsigned)f2bf(a) | ((unsigned)f2bf(b) << 16);
}
__device__ __forceinline__ float bflo(unsigned u) {
    return __builtin_bit_cast(float, u << 16);
}
__device__ __forceinline__ float bfhi(unsigned u) {
    return __builtin_bit_cast(float, u & 0xFFFF0000u);
}

typedef const __attribute__((address_space(1))) void gvoid_t;
typedef __attribute__((address_space(3))) void lvoid_t;
__device__ __forceinline__ void gload16(const void* g, void* l) {
    __builtin_amdgcn_global_load_lds((gvoid_t*)g, (lvoid_t*)l, 16, 0, 0);
}

// ---------------------------------------------------------------------------
// Kernel 0: Wt[n][k] = bf16(W[k][n]);  [128][1024] ushort.
// ---------------------------------------------------------------------------
__global__ void build_wt(const float* __restrict__ W, unsigned short* __restrict__ Wt) {
    int o = blockIdx.x * 256 + threadIdx.x;      // 131072
    int n = o >> 10, k = o & 1023;
    Wt[o] = f2bf(W[k * N_ + n]);
}

// ---------------------------------------------------------------------------
// Kernel 1: qk[m][0:128] = bf16( RoPE( A[m][:] @ W + b ) ), packed 2/uint.
// Block 256 = 4 waves; wave owns 16 rows x 128 cols (8 MFMA 16x16x32 tiles).
// A (fp32) and Wt (bf16) double-buffer-staged via global_load_lds (async DMA),
// XOR-swizzled on the GLOBAL side so LDS dest stays lane-contiguous.
// One barrier per K-chunk; prefetch issued right after it (m97 structure).
// ---------------------------------------------------------------------------
__launch_bounds__(256, 2)
__global__ void gemm_rope(const float* __restrict__ A,            // [M][1024]
                          const unsigned short* __restrict__ Wt,  // [128][1024] bf16
                          const float* __restrict__ bias,         // [128]
                          const int* __restrict__ pos_ids,        // [M]
                          unsigned* __restrict__ qk)              // [M][64] bf16x2
{
    __shared__ __align__(16) float          abuf[2][64 * 64];      // 2 x 16 KiB
    __shared__ __align__(16) unsigned short wbuf[2][N_ * 64];      // 2 x 16 KiB

    const int tid  = threadIdx.x;
    const int wave = tid >> 6, lane = tid & 63;
    const int ln15 = lane & 15, quad = lane >> 4, key = ln15 & 7;
    const int m0   = blockIdx.x * 64;

    // ---- staging address precompute (per lane)
    const float* a_g[4];
    const unsigned short* w_g[4];
    int a_lo[4], w_lo[4];
    #pragma unroll
    for (int t = 0; t < 4; t++) {
        const int rl = wave * 16 + t * 4 + (lane >> 4);            // A row in block
        a_g[t]  = A + (size_t)(m0 + rl) * H_ + (((lane & 15) ^ (rl & 7)) << 2);
        a_lo[t] = (wave * 16 + t * 4) * 64;                        // uniform LDS base (floats)
        const int n = (wave * 4 + t) * 8 + (lane >> 3);            // Wt row
        w_g[t]  = Wt + (size_t)n * 1024 + (((lane & 7) ^ (n & 7)) << 3);
        w_lo[t] = (wave * 4 + t) * 8 * 64;                         // uniform LDS base (shorts)
    }

    f32x4 acc[8];
    #pragma unroll
    for (int j = 0; j < 8; j++) acc[j] = (f32x4)0.f;

    // ---- prologue: stage chunk 0 into buf 0
    #pragma unroll
    for (int t = 0; t < 4; t++) {
        gload16(a_g[t], &abuf[0][a_lo[t]]);
        gload16(w_g[t], &wbuf[0][w_lo[t]]);
    }

    const float* ab_lane_base;  // set per buffer below
    for (int kc = 0; kc < NC_; kc++) {
        __syncthreads();                      // drains stage(kc) DMA; all waves ready
        if (kc + 1 < NC_) {                   // async prefetch overlaps full compute phase
            const int nb = (kc + 1) & 1;
            #pragma unroll
            for (int t = 0; t < 4; t++) {
                gload16(a_g[t] + (kc + 1) * 64, &abuf[nb][a_lo[t]]);
                gload16(w_g[t] + (kc + 1) * 64, &wbuf[nb][w_lo[t]]);
            }
        }
        const int cb = kc & 1;
        ab_lane_base = &abuf[cb][(wave * 16 + ln15) * 64];
        #pragma unroll
        for (int ks = 0; ks < 2; ks++) {
            const int g0 = ks * 8 + quad * 2;
            f32x4 r0 = *(const f32x4*)(ab_lane_base + ((g0 ^ key) << 2));
            f32x4 r1 = *(const f32x4*)(ab_lane_base + (((g0 + 1) ^ key) << 2));
            int4 ai;
            ai.x = (int)pk2(r0[0], r0[1]);
            ai.y = (int)pk2(r0[2], r0[3]);
            ai.z = (int)pk2(r1[0], r1[1]);
            ai.w = (int)pk2(r1[2], r1[3]);
            const short8 af = __builtin_bit_cast(short8, ai);
            const int p = ((ks * 4 + quad) ^ key) << 3;
            #pragma unroll
            for (int j = 0; j < 8; j++) {
                const short8 bf = *(const short8*)(&wbuf[cb][(j * 16 + ln15) * 64 + p]);
                acc[j] = __builtin_amdgcn_mfma_f32_16x16x32_bf16(af, bf, acc[j], 0, 0, 0);
            }
        }
    }

    // ---- epilogue: bias + RoPE (v_sin/v_cos in revolutions) + packed bf16 store
    // C/D layout: col = ln15 (within tile j), row = quad*4 + reg
    const int rbase = m0 + wave * 16 + quad * 4;
    float bv[8], invr[4];
    #pragma unroll
    for (int j = 0; j < 8; j++) bv[j] = bias[j * 16 + ln15];
    #pragma unroll
    for (int jj = 0; jj < 4; jj++) {
        const float fi = (float)((jj * 16 + ln15) >> 1);
        // inv_freq/(2pi) = exp2(-fi*log2(10000)/32) * 0.15915494
        invr[jj] = exp2f(fi * -0.41524101186092029f) * 0.15915494309189535f;
    }
    const bool odd = (ln15 & 1);
    #pragma unroll
    for (int reg = 0; reg < 4; reg++) {
        const int r = rbase + reg;
        const float pos = (float)pos_ids[r];
        #pragma unroll
        for (int j = 0; j < 8; j++) {
            const int c = j * 16 + ln15;
            float v = acc[j][reg] + bv[j];
            float p = __shfl_xor(v, 1, 64);                 // partner column c^1
            float fr = __builtin_amdgcn_fractf(pos * invr[j & 3]);
            float s  = __builtin_amdgcn_sinf(fr);
            float co = __builtin_amdgcn_cosf(fr);
            float outv = odd ? fmaf(v, co, p * s) : fmaf(v, co, -p * s);
            float po = __shfl_xor(outv, 1, 64);
            if (!odd)
                qk[(size_t)r * 64 + (c >> 1)] = pk2(outv, po);
        }
    }
}

// ---------------------------------------------------------------------------
// Kernel 2: one wave per relation; qk is packed bf16 pairs.
// lanes 0..31: qw[i0] . kw[i2];  lanes 32..63: qw[i1] . kw[i3]
// ---------------------------------------------------------------------------
__global__ void gather_dot(const unsigned* __restrict__ qk, const int* __restrict__ rel,
                           const float* __restrict__ mask, float* __restrict__ out)
{
    const int w    = (blockIdx.x * 256 + threadIdx.x) >> 6;   // 0..32767
    const int lane = threadIdx.x & 63;
    const int b    = w >> 11;
    const int4 id4 = ((const int4*)rel)[w];
    const unsigned* base = qk + (size_t)b * S_ * 64;
    const int rq  = (lane < 32) ? id4.x : id4.y;
    const int rk  = (lane < 32) ? id4.z : id4.w;
    const int col = lane & 31;
    const unsigned uq = base[(size_t)rq * 64 + col];
    const unsigned uk = base[(size_t)rk * 64 + 32 + col];
    float v = bflo(uq) * bflo(uk) + bfhi(uq) * bfhi(uk);
    #pragma unroll
    for (int off = 32; off; off >>= 1) v += __shfl_xor(v, off, 64);
    if (lane == 0)
        out[w] = (v + (1.0f - mask[w]) * -1e12f) * 0.125f;
}

// ---------------------------------------------------------------------------
extern "C" void kernel_launch(void* const* d_in, const int* in_sizes, int n_in,
                              void* d_out, int out_size, void* d_ws, size_t ws_size,
                              hipStream_t stream) {
    const float* lhs  = (const float*)d_in[0];   // (B,S,H) fp32
    const float* W    = (const float*)d_in[1];   // (H,128) fp32
    const float* bias = (const float*)d_in[2];   // (128,)  fp32
    const int*   pos  = (const int*)d_in[3];     // (B,S)   int32
    const int*   rel  = (const int*)d_in[4];     // (B,R,4) int32
    const float* mask = (const float*)d_in[5];   // (B,R)   fp32
    float* out = (float*)d_out;                  // (B,R)   fp32

    unsigned short* Wt = (unsigned short*)d_ws;                      // 256 KiB
    unsigned* qk = (unsigned*)((char*)d_ws + (size_t)N_ * H_ * 2);   // 8 MiB bf16 pairs

    build_wt<<<512, 256, 0, stream>>>(W, Wt);
    gemm_rope<<<512, 256, 0, stream>>>(lhs, Wt, bias, pos, qk);
    gather_dot<<<8192, 256, 0, stream>>>(qk, rel, mask, out);
}